// Round 4
// baseline (1295.909 us; speedup 1.0000x reference)
//
#include <hip/hip_runtime.h>

typedef __attribute__((ext_vector_type(8))) short short8;
typedef __attribute__((ext_vector_type(4))) float float4v;
typedef __attribute__((ext_vector_type(4))) unsigned int uint4v;
typedef unsigned short ushort_t;

#define MFMA16(A,B,C) __builtin_amdgcn_mfma_f32_16x16x32_bf16((A),(B),(C),0,0,0)

// ---- LDS layout (byte offsets, 16-aligned; ENTIRE region zeroed in P0a) ----
// EQK: 256 rows x 64 B: [t]: bytes[0,32)=rel_hi[i=0..15], [32,64)=rel_lo[i]  (rel col 254-t)
// KT:  128 rows x 32 B: [j][i]: i<8 k_hi[i][j]; i in [8,16) stays ZERO
// QH:  128 rows x 32 B: [d][i]: i<8 q_hi*scale, i in [8,16) k_hi
// QL:  128 rows x 32 B: same but lo residuals
// EVV: 16 rows x 768 B: [i]: u<255 rel_v=rel[16+i][254-u] bf16; u=255 zero; u in [256,384): v[i][u-256]
// S:   32 slots x 512 B f32 scores S[d&31][j]; after softmax, attn bf16 aliases bytes [0,256)
#define OFF_EQK   0
#define OFF_KT    16384
#define OFF_QH    20480
#define OFF_QL    24576
#define OFF_EVV   28672
#define OFF_IB    40960   // 32 x {inv, b0} f32
#define OFF_S     41216
#define OFF_ZB    57600   // 16 B zeros for MFMA K-padding reads
#define LDS_BYTES 57616

__device__ __forceinline__ ushort_t f2bf(float f) {
  unsigned u = __builtin_bit_cast(unsigned, f);
  u += 0x7fffu + ((u >> 16) & 1u);          // RNE
  return (ushort_t)(u >> 16);
}
__device__ __forceinline__ float bf2f(ushort_t s) {
  return __builtin_bit_cast(float, ((unsigned)s) << 16);
}

__global__ __launch_bounds__(512, 4) void axial_fused(
    const float* __restrict__ xg,      // (2048,128,128) f32
    const float* __restrict__ wg,      // (256,128) f32
    const float* __restrict__ gg, const float* __restrict__ btg,
    const float* __restrict__ mng, const float* __restrict__ vrg,
    const float* __restrict__ relg,    // (32,255) f32
    float* __restrict__ outg)          // (2048,128,128) f32 out
{
  __shared__ __align__(16) char L[LDS_BYTES];
  const int tid  = threadIdx.x;
  const int b    = blockIdx.x >> 3;
  const int h    = blockIdx.x & 7;
  const int w    = tid >> 6;          // wave 0..7
  const int lane = tid & 63;
  const int q    = lane >> 4;         // quad 0..3
  const int m16  = lane & 15;
  const char* zb = L + OFF_ZB;
  const short8 zfrag = {0,0,0,0,0,0,0,0};

  // ---------- P0a: zero the ENTIRE LDS region ----------
  for (int k4 = tid; k4 < 3601; k4 += 512)
    ((uint4v*)L)[k4] = (uint4v){0u,0u,0u,0u};
  __syncthreads();

  // ---------- P0b: rel gather (hi/lo) + BN params ----------
  for (int e = tid; e < 4096; e += 512) {
    int i = e >> 8, m = e & 255;
    if (m < 255) {
      int t = 254 - m;
      float r1 = relg[i * 255 + m];
      ushort_t h1 = f2bf(r1);
      *(ushort_t*)(L + OFF_EQK + t * 64 + i * 2)      = h1;
      *(ushort_t*)(L + OFF_EQK + t * 64 + 32 + i * 2) = f2bf(r1 - bf2f(h1));
      float r2 = relg[(16 + i) * 255 + m];
      *(ushort_t*)(L + OFF_EVV + i * 768 + t * 2) = f2bf(r2);
    }
  }
  if (tid < 32) {
    int og = tid * 8 + h;
    float inv = gg[og] / sqrtf(vrg[og] + 1e-5f);
    ((float*)(L + OFF_IB))[tid * 2]     = inv;
    ((float*)(L + OFF_IB))[tid * 2 + 1] = btg[og] - mng[og] * inv;
  }
  __syncthreads();

  // ---------- P1: conv + BN with hi/lo split: y[o][d] = sum_c w[o][c]*x[c][d] ----------
  {
    const int d = w * 16 + m16;
    float4v acc0 = {0,0,0,0}, acc1 = {0,0,0,0};
    const float* xb = xg + (size_t)b * 16384;
    const int og0 = m16 * 8 + h, og1 = (16 + m16) * 8 + h;
    for (int cc = 0; cc < 4; ++cc) {
      int cb = cc * 32;
      short8 xh, xl, wh0, wl0, wh1, wl1;
      const float* wp0 = wg + og0 * 128 + cb + q * 8;
      const float* wp1 = wg + og1 * 128 + cb + q * 8;
      #pragma unroll
      for (int jj = 0; jj < 8; ++jj) {
        float xv = xb[(cb + q * 8 + jj) * 128 + d];
        ushort_t xhv = f2bf(xv);
        xh[jj] = (short)xhv; xl[jj] = (short)f2bf(xv - bf2f(xhv));
        float w0 = wp0[jj];
        ushort_t w0h = f2bf(w0);
        wh0[jj] = (short)w0h; wl0[jj] = (short)f2bf(w0 - bf2f(w0h));
        float w1 = wp1[jj];
        ushort_t w1h = f2bf(w1);
        wh1[jj] = (short)w1h; wl1[jj] = (short)f2bf(w1 - bf2f(w1h));
      }
      acc0 = MFMA16(wh0, xh, acc0);
      acc0 = MFMA16(wl0, xh, acc0);
      acc0 = MFMA16(wh0, xl, acc0);
      acc1 = MFMA16(wh1, xh, acc1);
      acc1 = MFMA16(wl1, xh, acc1);
      acc1 = MFMA16(wh1, xl, acc1);
    }
    const float* ib = (const float*)(L + OFF_IB);
    #pragma unroll
    for (int mm = 0; mm < 2; ++mm) {
      float4v a = mm ? acc1 : acc0;
      #pragma unroll
      for (int r = 0; r < 4; ++r) {
        int o = mm * 16 + q * 4 + r;               // qkv channel; this lane's d = col = m16 (d above)
        float y = a[r] * ib[o * 2] + ib[o * 2 + 1];
        if (o < 8) {
          float qs = y * 0.08838834764831845f;
          ushort_t hq = f2bf(qs);
          *(ushort_t*)(L + OFF_QH + d * 32 + o * 2) = hq;
          *(ushort_t*)(L + OFF_QL + d * 32 + o * 2) = f2bf(qs - bf2f(hq));
        } else if (o < 16) {
          ushort_t hk = f2bf(y);
          *(ushort_t*)(L + OFF_QH + d * 32 + o * 2) = hk;
          *(ushort_t*)(L + OFF_QL + d * 32 + o * 2) = f2bf(y - bf2f(hk));
          *(ushort_t*)(L + OFF_KT + d * 32 + (o - 8) * 2) = hk;
        } else {
          *(ushort_t*)(L + OFF_EVV + (o - 16) * 768 + (256 + d) * 2) = f2bf(y);
        }
      }
    }
  }
  __syncthreads();

  // ---------- P2: attention in 4 d-blocks of 32 rows ----------
  for (int it = 0; it < 4; ++it) {
    const int d0b = it * 32;
    const int bo = (q & 1) * 16;   // q>=2 lanes re-read the low half (K-duplication)
    short8 bh0 = *(const short8*)(L + OFF_QH + (d0b + m16) * 32 + bo);
    short8 bh1 = *(const short8*)(L + OFF_QH + (d0b + 16 + m16) * 32 + bo);
    short8 bl0 = *(const short8*)(L + OFF_QL + (d0b + m16) * 32 + bo);
    short8 bl1 = *(const short8*)(L + OFF_QL + (d0b + 16 + m16) * 32 + bo);

    // dots: D[m=j][n=d] = sum_{i<8} k_hi[i][j] * q_hi*s[i][d]  (A upper half zero)
    {
      short8 af = *(const short8*)((q < 2) ? (L + OFF_KT + (w * 16 + m16) * 32 + q * 16) : zb);
      float4v z = {0,0,0,0};
      float4v c0 = MFMA16(af, bh0, z);
      float4v c1 = MFMA16(af, bh1, z);
      int j0 = w * 16 + q * 4;
      *(float4v*)(L + OFF_S + m16 * 512 + j0 * 4) = c0;
      *(float4v*)(L + OFF_S + (16 + m16) * 512 + j0 * 4) = c1;
    }
    __syncthreads();

    // t-part: T[t][d] = (rel_hi+rel_lo)·qk_hi + rel_hi·qk_lo ; S[d][t-127+d] += T
    {
      const int nlo = 6 - it * 2;
      const int npass = (w < 2) ? 2 : 1;
      for (int pp = 0; pp < npass; ++pp) {
        int t0 = (nlo + w + pp * 8) * 16;
        short8 a1 = *(const short8*)(L + OFF_EQK + (t0 + m16) * 64 + q * 16); // [hi|lo]
        short8 a2 = (q < 2) ? a1 : zfrag;                                    // [hi|0]
        float4v z = {0,0,0,0};
        float4v c0 = MFMA16(a1, bh0, z); c0 = MFMA16(a2, bl0, c0);
        float4v c1 = MFMA16(a1, bh1, z); c1 = MFMA16(a2, bl1, c1);
        #pragma unroll
        for (int dn = 0; dn < 2; ++dn) {
          float4v c = dn ? c1 : c0;
          int d = d0b + dn * 16 + m16;
          char* slot = L + OFF_S + (d & 31) * 512;
          #pragma unroll
          for (int r = 0; r < 4; ++r) {
            int j = t0 + q * 4 + r - 127 + d;     // unique (slot,j) per lane/reg
            if ((unsigned)j < 128u) {
              float* p = (float*)(slot + j * 4);
              *p += c[r];
            }
          }
        }
      }
    }
    __syncthreads();

    // softmax per row; attn bf16 aliases bytes [0,256) of the slot.
    // Safe: writes data-depend on the reads (per-wave in-order LDS).
    #pragma unroll 1
    for (int rr = 0; rr < 4; ++rr) {
      int d = d0b + w * 4 + rr;
      char* slot = L + OFF_S + (d & 31) * 512;
      float v0 = *(float*)(slot + lane * 4);
      float v1 = *(float*)(slot + (64 + lane) * 4);
      float mx = fmaxf(v0, v1);
      #pragma unroll
      for (int off = 32; off; off >>= 1) mx = fmaxf(mx, __shfl_xor(mx, off, 64));
      float e0 = __expf(v0 - mx), e1 = __expf(v1 - mx);
      float sm = e0 + e1;
      #pragma unroll
      for (int off = 32; off; off >>= 1) sm += __shfl_xor(sm, off, 64);
      float rs = 1.0f / sm;
      *(ushort_t*)(slot + lane * 2)       = f2bf(e0 * rs);
      *(ushort_t*)(slot + 128 + lane * 2) = f2bf(e1 * rs);
    }
    __syncthreads();

    // out+kv GEMM (waves 0,1): D[m=d][n=i]; K = 256 (kv, shifted A) + 128 (out)
    if (w < 2) {
      const int dbase = d0b + w * 16;
      const int d = dbase + m16;                    // A-row for this lane
      char* ab = L + OFF_S + (d & 31) * 512;        // attn row bf16 at bytes [0,256)
      const char* evrow = L + OFF_EVV + m16 * 768;  // B col n=i=m16
      float4v acc = {0,0,0,0};
      #pragma unroll 1
      for (int ks = 0; ks < 8; ++ks) {              // kv: A[d][u] = attn[d][u-127+d]
        short8 af;
        #pragma unroll
        for (int jj = 0; jj < 8; ++jj) {
          int j = ks * 32 + q * 8 + jj - 127 + d;
          ushort_t vv = 0;
          if ((unsigned)j < 128u) vv = *(ushort_t*)(ab + j * 2);
          af[jj] = (short)vv;
        }
        short8 bf = *(const short8*)(evrow + (ks * 32 + q * 8) * 2);
        acc = MFMA16(af, bf, acc);
      }
      #pragma unroll
      for (int ks = 0; ks < 4; ++ks) {              // out: A[d][j] = attn[d][j]
        short8 af = *(const short8*)(ab + (ks * 32 + q * 8) * 2);
        short8 bf = *(const short8*)(evrow + (256 + ks * 32 + q * 8) * 2);
        acc = MFMA16(af, bf, acc);
      }
      // D rows = dbase+q*4+r (consecutive d), col i=m16 -> one float4 global store
      float* op = outg + (size_t)b * 16384 + (h * 16 + m16) * 128 + dbase + q * 4;
      *(float4v*)op = acc;
    }
    __syncthreads();
  }
}

extern "C" void kernel_launch(void* const* d_in, const int* in_sizes, int n_in,
                              void* d_out, int out_size, void* d_ws, size_t ws_size,
                              hipStream_t stream) {
  const float* xg   = (const float*)d_in[0];
  const float* wg   = (const float*)d_in[1];
  const float* gg   = (const float*)d_in[2];
  const float* btg  = (const float*)d_in[3];
  const float* mng  = (const float*)d_in[4];
  const float* vrg  = (const float*)d_in[5];
  const float* relg = (const float*)d_in[6];
  float* outg = (float*)d_out;
  axial_fused<<<dim3(16384), dim3(512), 0, stream>>>(xg, wg, gg, btg, mng, vrg, relg, outg);
}